// Round 2
// baseline (1640.944 us; speedup 1.0000x reference)
//
#include <hip/hip_runtime.h>

#define HEADS 8
#define NHID 128
#define NLAST 64
#define MNODES 400
#define ENUM 256
#define NNODES 512
#define LSEQ 256
#define HDIM 768
#define PAIRS 2048
#define NEDGE 4096
#define HMID 1024

// ---- monotonic float<->uint encode for atomicMax-based segment max ----
__device__ inline unsigned enc_f(float x){
  unsigned b = __float_as_uint(x);
  return (b & 0x80000000u) ? ~b : (b | 0x80000000u);
}
__device__ inline float dec_f(unsigned e){
  unsigned b = (e & 0x80000000u) ? (e & 0x7FFFFFFFu) : ~e;
  return __uint_as_float(b);
}

// merged = segment_mean(node_s_emb[n, node_e[n], :], co_id)  (numerator + count)
__global__ void k_merge(const float* __restrict__ node_s_emb, const int* __restrict__ node_e,
                        const int* __restrict__ co_id, float* merged, float* cnt){
  int n = blockIdx.x;
  int co = co_id[n];
  const float* src = node_s_emb + ((size_t)n*LSEQ + node_e[n])*(size_t)HDIM;
  float* dst = merged + (size_t)co*HDIM;
  for(int j = threadIdx.x; j < HDIM; j += blockDim.x)
    atomicAdd(&dst[j], src[j]);
  if(threadIdx.x == 0) atomicAdd(&cnt[co], 1.0f);
}

// rows /= max(cnt,1)
__global__ void k_divrows(float* x, const float* __restrict__ cnt, int cols){
  int r = blockIdx.x;
  float inv = 1.0f / fmaxf(cnt[r], 1.0f);
  for(int j = threadIdx.x; j < cols; j += blockDim.x)
    x[(size_t)r*cols + j] *= inv;
}

// node degree D (over n_idx) and edge degree B (over e_idx)
__global__ void k_deg(const int* __restrict__ n_idx, const int* __restrict__ e_idx,
                      float* Ddeg, float* Bdeg){
  int k = blockIdx.x*blockDim.x + threadIdx.x;
  if(k >= NEDGE) return;
  atomicAdd(&Ddeg[n_idx[k]], 1.0f);
  atomicAdd(&Bdeg[e_idx[k]], 1.0f);
}

// s[e_idx[k]] += x[n_idx[k]]  (edge_mean numerator)
__global__ void k_edge_gather(const float* __restrict__ x, const int* __restrict__ n_idx,
                              const int* __restrict__ e_idx, float* s, int cols){
  int k = blockIdx.x;
  int n = n_idx[k], e = e_idx[k];
  const float* src = x + (size_t)n*cols;
  float* dst = s + (size_t)e*cols;
  for(int j = threadIdx.x; j < cols; j += blockDim.x)
    atomicAdd(&dst[j], src[j]);
}

// C[M,N] = A[M,K] @ B[K,N] (+bias, +relu). N%64==0, K%16==0; M guarded.
#define BM 64
#define BN 64
#define BK 16
__global__ __launch_bounds__(256) void k_gemm(const float* __restrict__ A, const float* __restrict__ B,
                                              float* C, int M, int N, int K,
                                              const float* __restrict__ bias, int relu){
  __shared__ float As[BK][BM];
  __shared__ float Bs[BK][BN];
  int tx = threadIdx.x % 16, ty = threadIdx.x / 16;
  int row0 = blockIdx.y*BM, col0 = blockIdx.x*BN;
  float acc[4][4] = {};
  for(int k0 = 0; k0 < K; k0 += BK){
    for(int t = threadIdx.x; t < BM*BK; t += 256){
      int r = t / BK, c = t % BK;
      int gr = row0 + r;
      As[c][r] = (gr < M) ? A[(size_t)gr*K + (k0 + c)] : 0.0f;
    }
    for(int t = threadIdx.x; t < BK*BN; t += 256){
      int r = t / BN, c = t % BN;
      Bs[r][c] = B[(size_t)(k0 + r)*N + (col0 + c)];
    }
    __syncthreads();
    #pragma unroll
    for(int k = 0; k < BK; k++){
      float a[4], b[4];
      #pragma unroll
      for(int i = 0; i < 4; i++) a[i] = As[k][ty*4 + i];
      #pragma unroll
      for(int j = 0; j < 4; j++) b[j] = Bs[k][tx*4 + j];
      #pragma unroll
      for(int i = 0; i < 4; i++)
        #pragma unroll
        for(int j = 0; j < 4; j++) acc[i][j] += a[i]*b[j];
    }
    __syncthreads();
  }
  for(int i = 0; i < 4; i++){
    int gr = row0 + ty*4 + i;
    if(gr >= M) continue;
    for(int j = 0; j < 4; j++){
      int gc = col0 + tx*4 + j;
      float v = acc[i][j];
      if(bias) v += bias[gc];
      if(relu) v = fmaxf(v, 0.0f);
      C[(size_t)gr*N + gc] = v;
    }
  }
}

// alpha[e,h] = leaky_relu(sum_c att[h,c]*xw[n,h,c] + att[h,oc+c]*ew[e,h,c]); atomicMax into amax
__global__ void k_alpha(const float* __restrict__ xw, const float* __restrict__ ew,
                        const float* __restrict__ att, const int* __restrict__ n_idx,
                        const int* __restrict__ e_idx, float* alpha, unsigned* amax, int oc){
  int k = blockIdx.x;
  int h = threadIdx.x / 32;
  int lane = threadIdx.x % 32;
  int n = n_idx[k], e = e_idx[k];
  const float* xr = xw + ((size_t)n*HEADS + h)*oc;
  const float* er = ew + ((size_t)e*HEADS + h)*oc;
  const float* at = att + (size_t)h*2*oc;
  float s = 0.f;
  for(int c = lane; c < oc; c += 32) s += at[c]*xr[c] + at[oc + c]*er[c];
  for(int off = 16; off; off >>= 1) s += __shfl_xor(s, off, 32);
  if(lane == 0){
    float a = s > 0.f ? s : 0.2f*s;
    alpha[(size_t)k*HEADS + h] = a;
    atomicMax(&amax[n*HEADS + h], enc_f(a));
  }
}

// alpha <- exp(alpha - amax[n]); den[n] += exp
__global__ void k_expden(float* alpha, const unsigned* __restrict__ amax,
                         float* den, const int* __restrict__ n_idx){
  int t = blockIdx.x*blockDim.x + threadIdx.x;
  if(t >= NEDGE*HEADS) return;
  int k = t / HEADS, h = t % HEADS;
  int n = n_idx[k];
  float m = dec_f(amax[n*HEADS + h]);
  float ex = expf(alpha[t] - m);
  alpha[t] = ex;
  atomicAdd(&den[n*HEADS + h], ex);
}

// eout[e] += Binv[e] * alpha_sm * xw[n]
__global__ void k_msg1(const float* __restrict__ xw, const float* __restrict__ alpha,
                       const float* __restrict__ den, const float* __restrict__ Bdeg,
                       const int* __restrict__ n_idx, const int* __restrict__ e_idx,
                       float* eout, int oc){
  int k = blockIdx.x;
  int n = n_idx[k], e = e_idx[k];
  float bd = Bdeg[e];
  float binv = bd > 0.f ? 1.0f/fmaxf(bd, 1.0f) : 0.f;
  for(int t = threadIdx.x; t < HEADS*oc; t += blockDim.x){
    int h = t / oc;
    float a = alpha[(size_t)k*HEADS + h] / fmaxf(den[n*HEADS + h], 1e-16f);
    atomicAdd(&eout[(size_t)e*HEADS*oc + t], binv*a*xw[(size_t)n*HEADS*oc + t]);
  }
}

// hout[n] += Dinv[n] * alpha_sm * eout[e]
__global__ void k_msg2(const float* __restrict__ eout, const float* __restrict__ alpha,
                       const float* __restrict__ den, const float* __restrict__ Ddeg,
                       const int* __restrict__ n_idx, const int* __restrict__ e_idx,
                       float* hout, int oc){
  int k = blockIdx.x;
  int n = n_idx[k], e = e_idx[k];
  float dd = Ddeg[n];
  float dinv = dd > 0.f ? 1.0f/fmaxf(dd, 1.0f) : 0.f;
  for(int t = threadIdx.x; t < HEADS*oc; t += blockDim.x){
    int h = t / oc;
    float a = alpha[(size_t)k*HEADS + h] / fmaxf(den[n*HEADS + h], 1e-16f);
    atomicAdd(&hout[(size_t)n*HEADS*oc + t], dinv*a*eout[(size_t)e*HEADS*oc + t]);
  }
}

// x[r,:] = (x[r,:] + b) (relu?)
__global__ void k_biasact(float* x, const float* __restrict__ b, int cols, int relu){
  int r = blockIdx.x;
  for(int j = threadIdx.x; j < cols; j += blockDim.x){
    float v = x[(size_t)r*cols + j] + b[j];
    if(relu) v = fmaxf(v, 0.f);
    x[(size_t)r*cols + j] = v;
  }
}

// feat[p] = [a+b, a-b, e1, e2]
__global__ void k_feat(const float* __restrict__ h2, const float* __restrict__ sent_emb,
                       const int* __restrict__ pair_doc, const int* __restrict__ event_e,
                       const int* __restrict__ event_id, const int* __restrict__ co_id,
                       float* feat){
  int p = blockIdx.x;
  int ia = co_id[event_id[p*2 + 0]];
  int ib = co_id[event_id[p*2 + 1]];
  const float* ha = h2 + (size_t)ia*512;
  const float* hb = h2 + (size_t)ib*512;
  float* f = feat + (size_t)p*2560;
  for(int j = threadIdx.x; j < 512; j += blockDim.x){
    float a = ha[j], b = hb[j];
    f[j] = a + b;
    f[512 + j] = a - b;
  }
  const float* e1 = sent_emb + ((size_t)pair_doc[p]*LSEQ + event_e[p*2 + 0])*(size_t)HDIM;
  const float* e2 = sent_emb + ((size_t)pair_doc[p]*LSEQ + event_e[p*2 + 1])*(size_t)HDIM;
  for(int j = threadIdx.x; j < HDIM; j += blockDim.x){
    f[1024 + j] = e1[j];
    f[1024 + HDIM + j] = e2[j];
  }
}

// out[p,:2] = hid[p,:] @ Wm2 + bm2
__global__ void k_final(const float* __restrict__ hid, const float* __restrict__ Wm2,
                        const float* __restrict__ bm2, float* out){
  int p = blockIdx.x;
  float s0 = 0.f, s1 = 0.f;
  for(int k = threadIdx.x; k < HMID; k += blockDim.x){
    float h = hid[(size_t)p*HMID + k];
    s0 += h*Wm2[k*2 + 0];
    s1 += h*Wm2[k*2 + 1];
  }
  __shared__ float r0[256], r1[256];
  r0[threadIdx.x] = s0; r1[threadIdx.x] = s1;
  __syncthreads();
  for(int off = 128; off; off >>= 1){
    if(threadIdx.x < off){ r0[threadIdx.x] += r0[threadIdx.x + off]; r1[threadIdx.x] += r1[threadIdx.x + off]; }
    __syncthreads();
  }
  if(threadIdx.x == 0){
    out[p*2 + 0] = r0[0] + bm2[0];
    out[p*2 + 1] = r1[0] + bm2[1];
  }
}

extern "C" void kernel_launch(void* const* d_in, const int* in_sizes, int n_in,
                              void* d_out, int out_size, void* d_ws, size_t ws_size,
                              hipStream_t stream) {
  const float* sent_emb   = (const float*)d_in[0];
  const float* node_s_emb = (const float*)d_in[1];
  const float* W1   = (const float*)d_in[2];
  const float* att1 = (const float*)d_in[3];
  const float* b1   = (const float*)d_in[4];
  const float* W2   = (const float*)d_in[5];
  const float* att2 = (const float*)d_in[6];
  const float* b2   = (const float*)d_in[7];
  const float* Wm1  = (const float*)d_in[8];
  const float* bm1  = (const float*)d_in[9];
  const float* Wm2  = (const float*)d_in[10];
  const float* bm2  = (const float*)d_in[11];
  const int* pair_doc = (const int*)d_in[12];
  const int* event_e  = (const int*)d_in[13];
  const int* node_e   = (const int*)d_in[14];
  const int* co_id    = (const int*)d_in[15];
  const int* hyper    = (const int*)d_in[16];
  const int* event_id = (const int*)d_in[17];
  const int* n_idx = hyper;            // hyperedge_index row 0
  const int* e_idx = hyper + NEDGE;    // hyperedge_index row 1

  float* w = (float*)d_ws;
  size_t off = 0;
  auto alloc = [&](size_t n){ float* p = w + off; off += n; return p; };

  float* merged = alloc((size_t)MNODES*HDIM);
  float* cnt_co = alloc(MNODES);
  float* Ddeg   = alloc(MNODES);
  float* Bdeg   = alloc(ENUM);
  float* eattr1 = alloc((size_t)ENUM*HDIM);
  float* xw1    = alloc((size_t)MNODES*HEADS*NHID);
  float* ew1    = alloc((size_t)ENUM*HEADS*NHID);
  float* alpha1 = alloc((size_t)NEDGE*HEADS);
  float* amax1f = alloc((size_t)MNODES*HEADS);
  float* den1   = alloc((size_t)MNODES*HEADS);
  float* eout1  = alloc((size_t)ENUM*HEADS*NHID);
  float* h1     = alloc((size_t)MNODES*HEADS*NHID);
  float* eattr2 = alloc((size_t)ENUM*HEADS*NHID);
  float* xw2    = alloc((size_t)MNODES*HEADS*NLAST);
  float* ew2    = alloc((size_t)ENUM*HEADS*NLAST);
  float* alpha2 = alloc((size_t)NEDGE*HEADS);
  float* amax2f = alloc((size_t)MNODES*HEADS);
  float* den2   = alloc((size_t)MNODES*HEADS);
  float* eout2  = alloc((size_t)ENUM*HEADS*NLAST);
  float* h2     = alloc((size_t)MNODES*HEADS*NLAST);
  float* feat   = alloc((size_t)PAIRS*2560);
  float* hid    = alloc((size_t)PAIRS*HMID);
  unsigned* amax1 = (unsigned*)amax1f;
  unsigned* amax2 = (unsigned*)amax2f;

  // zero all accumulators (ws is poisoned 0xAA before every launch)
  hipMemsetAsync(d_ws, 0, off*sizeof(float), stream);

  // segment-mean merged nodes
  k_merge<<<NNODES, 256, 0, stream>>>(node_s_emb, node_e, co_id, merged, cnt_co);
  k_divrows<<<MNODES, 256, 0, stream>>>(merged, cnt_co, HDIM);
  k_deg<<<(NEDGE + 255)/256, 256, 0, stream>>>(n_idx, e_idx, Ddeg, Bdeg);

  // ---- layer 1 ----
  k_edge_gather<<<NEDGE, 256, 0, stream>>>(merged, n_idx, e_idx, eattr1, HDIM);
  k_divrows<<<ENUM, 256, 0, stream>>>(eattr1, Bdeg, HDIM);
  k_gemm<<<dim3(HEADS*NHID/BN, (MNODES + BM - 1)/BM), 256, 0, stream>>>(merged, W1, xw1, MNODES, HEADS*NHID, HDIM, nullptr, 0);
  k_gemm<<<dim3(HEADS*NHID/BN, (ENUM + BM - 1)/BM), 256, 0, stream>>>(eattr1, W1, ew1, ENUM, HEADS*NHID, HDIM, nullptr, 0);
  k_alpha<<<NEDGE, 256, 0, stream>>>(xw1, ew1, att1, n_idx, e_idx, alpha1, amax1, NHID);
  k_expden<<<(NEDGE*HEADS + 255)/256, 256, 0, stream>>>(alpha1, amax1, den1, n_idx);
  k_msg1<<<NEDGE, 256, 0, stream>>>(xw1, alpha1, den1, Bdeg, n_idx, e_idx, eout1, NHID);
  k_msg2<<<NEDGE, 256, 0, stream>>>(eout1, alpha1, den1, Ddeg, n_idx, e_idx, h1, NHID);
  k_biasact<<<MNODES, 256, 0, stream>>>(h1, b1, HEADS*NHID, 1);

  // ---- layer 2 ----
  k_edge_gather<<<NEDGE, 256, 0, stream>>>(h1, n_idx, e_idx, eattr2, HEADS*NHID);
  k_divrows<<<ENUM, 256, 0, stream>>>(eattr2, Bdeg, HEADS*NHID);
  k_gemm<<<dim3(HEADS*NLAST/BN, (MNODES + BM - 1)/BM), 256, 0, stream>>>(h1, W2, xw2, MNODES, HEADS*NLAST, HEADS*NHID, nullptr, 0);
  k_gemm<<<dim3(HEADS*NLAST/BN, (ENUM + BM - 1)/BM), 256, 0, stream>>>(eattr2, W2, ew2, ENUM, HEADS*NLAST, HEADS*NHID, nullptr, 0);
  k_alpha<<<NEDGE, 256, 0, stream>>>(xw2, ew2, att2, n_idx, e_idx, alpha2, amax2, NLAST);
  k_expden<<<(NEDGE*HEADS + 255)/256, 256, 0, stream>>>(alpha2, amax2, den2, n_idx);
  k_msg1<<<NEDGE, 256, 0, stream>>>(xw2, alpha2, den2, Bdeg, n_idx, e_idx, eout2, NLAST);
  k_msg2<<<NEDGE, 256, 0, stream>>>(eout2, alpha2, den2, Ddeg, n_idx, e_idx, h2, NLAST);
  k_biasact<<<MNODES, 256, 0, stream>>>(h2, b2, HEADS*NLAST, 0);

  // ---- pair MLP ----
  k_feat<<<PAIRS, 256, 0, stream>>>(h2, sent_emb, pair_doc, event_e, event_id, co_id, feat);
  k_gemm<<<dim3(HMID/BN, PAIRS/BM), 256, 0, stream>>>(feat, Wm1, hid, PAIRS, HMID, 2*HEADS*NLAST + 2*HDIM, bm1, 1);
  k_final<<<PAIRS, 256, 0, stream>>>(hid, Wm2, bm2, (float*)d_out);
}